// Round 2
// 547.993 us; speedup vs baseline: 1.0057x; 1.0057x over previous
//
#include <hip/hip_runtime.h>
#include <hip/hip_bf16.h>

#define H 1024
#define I_DIM 704
#define E 32
#define TOPK_GROUP 3
#define K_TOP 6
#define T_TOK 2048
#define CAP 768
#define IS_DIM 1408   // N_SHARED * I
#define NCHUNK 192    // (T_TOK*K_TOP)/64

typedef __attribute__((ext_vector_type(8))) short short8v;
typedef __attribute__((ext_vector_type(4))) float f32x4;

__device__ __forceinline__ unsigned short f2bfbits(float f) {
  unsigned u = __float_as_uint(f);
  unsigned r = (u + 0x7fffu + ((u >> 16) & 1u)) >> 16;  // RTNE
  return (unsigned short)r;
}
__device__ __forceinline__ unsigned packbf2(float lo, float hi) {
  __hip_bfloat162 h = __float22bfloat162_rn(make_float2(lo, hi));
  unsigned u; __builtin_memcpy(&u, &h, 4); return u;
}
__device__ __forceinline__ float bf2f(unsigned short b) {
  return __uint_as_float(((unsigned)b) << 16);
}
__device__ __forceinline__ void gload_lds16(const short* g, short* l) {
  __builtin_amdgcn_global_load_lds(
      (const __attribute__((address_space(1))) unsigned int*)g,
      (__attribute__((address_space(3))) unsigned int*)l, 16, 0, 0);
}

// ---------------- cast x (fp32) -> bf16 bits ----------------
__global__ void cast_x_kernel(const float* __restrict__ x, short* __restrict__ xb) {
  size_t i = ((size_t)blockIdx.x * 256 + threadIdx.x) * 4;
  float4 v = *(const float4*)(x + i);
  short4 s;
  s.x = (short)f2bfbits(v.x); s.y = (short)f2bfbits(v.y);
  s.z = (short)f2bfbits(v.z); s.w = (short)f2bfbits(v.w);
  *(short4*)(xb + i) = s;
}

// ---------------- gating: fp64 logits, lane-parallel softmax + group top-3 + top-6 ----------------
__global__ __launch_bounds__(64) void gating_kernel(const float* __restrict__ x,
                                                    const float* __restrict__ gw,
                                                    int* __restrict__ tidx,
                                                    float* __restrict__ tw) {
  int t = blockIdx.x;
  int lane = threadIdx.x;
  int e = lane & 31, half = lane >> 5;
  const float4* xr4 = (const float4*)(x + (size_t)t * H + half * 512);
  const float4* wr4 = (const float4*)(gw + (size_t)e * H + half * 512);
  double acc = 0.0;
  #pragma unroll 4
  for (int j = 0; j < 128; ++j) {
    float4 a = xr4[j], b = wr4[j];
    acc += (double)a.x * b.x + (double)a.y * b.y + (double)a.z * b.z + (double)a.w * b.w;
  }
  acc += __shfl_down(acc, 32);   // lanes 0..31 hold the 32 logits
  double lg = acc;
  double m = lg;
  #pragma unroll
  for (int off = 16; off >= 1; off >>= 1) {
    double o = __shfl_xor(m, off);
    if (o > m) m = o;
  }
  double p = exp(lg - m);
  double sum = p;
  #pragma unroll
  for (int off = 16; off >= 1; off >>= 1) sum += __shfl_xor(sum, off);
  p /= sum;
  double gmax = p;
  { double o = __shfl_xor(gmax, 1); if (o > gmax) gmax = o;
    o = __shfl_xor(gmax, 2); if (o > gmax) gmax = o; }
  bool gsel = false;
  double gv = gmax;
  #pragma unroll
  for (int it = 0; it < TOPK_GROUP; ++it) {
    double v = gv; int gi = e >> 2;
    #pragma unroll
    for (int off = 16; off >= 1; off >>= 1) {
      double ov = __shfl_xor(v, off);
      int oi = __shfl_xor(gi, off);
      if (ov > v || (ov == v && oi < gi)) { v = ov; gi = oi; }
    }
    if ((e >> 2) == gi) { gsel = true; gv = -1e300; }
  }
  double mp = gsel ? p : 0.0;
  #pragma unroll
  for (int it = 0; it < K_TOP; ++it) {
    double v = mp; int ei = e;
    #pragma unroll
    for (int off = 16; off >= 1; off >>= 1) {
      double ov = __shfl_xor(v, off);
      int oi = __shfl_xor(ei, off);
      if (ov > v || (ov == v && oi < ei)) { v = ov; ei = oi; }
    }
    if (lane == 0) { tidx[t * K_TOP + it] = ei; tw[t * K_TOP + it] = (float)v; }
    if (e == ei) mp = -2.0;
  }
}

// ---------------- dispatch phase 1: per-chunk histograms ----------------
__global__ __launch_bounds__(64) void hist_kernel(const int* __restrict__ tidx,
                                                  int* __restrict__ chunk_hist) {
  __shared__ int h[E];
  int c = blockIdx.x, lane = threadIdx.x;
  if (lane < E) h[lane] = 0;
  __syncthreads();
  int te = tidx[c * 64 + lane];
  atomicAdd(&h[te], 1);
  __syncthreads();
  if (lane < E) chunk_hist[c * E + lane] = h[lane];
}

// ---------------- dispatch phase 2: per-expert exclusive prefix over chunks ----------------
__global__ __launch_bounds__(1024) void scan_kernel(const int* __restrict__ chunk_hist,
                                                    int* __restrict__ chunk_base,
                                                    int* __restrict__ cnt) {
  __shared__ int h[NCHUNK * E];  // 24 KB
  int t = threadIdx.x;
  for (int i = t; i < NCHUNK * E; i += 1024) h[i] = chunk_hist[i];
  __syncthreads();
  if (t < E) {
    int run = 0;
    for (int c = 0; c < NCHUNK; ++c) {
      int v = h[c * E + t];
      h[c * E + t] = run;
      run += v;
    }
    cnt[t] = run < CAP ? run : CAP;
  }
  __syncthreads();
  for (int i = t; i < NCHUNK * E; i += 1024) chunk_base[i] = h[i];
}

// ---------------- dispatch phase 3: placement + inverse slot map ----------------
__global__ __launch_bounds__(64) void place_kernel(const int* __restrict__ tidx,
                                                   const int* __restrict__ chunk_base,
                                                   int* __restrict__ token_list,
                                                   int* __restrict__ sid) {
  int c = blockIdx.x, lane = threadIdx.x;
  int idx = c * 64 + lane;
  int te = tidx[idx];
  unsigned long long mymask = 0;
  #pragma unroll
  for (int e = 0; e < E; ++e) {
    unsigned long long bal = __ballot(te == e);
    if (te == e) mymask = bal;
  }
  int rank = __popcll(mymask & ((1ull << lane) - 1ull));
  int pos = chunk_base[c * E + te] + rank;
  int s = -1;
  if (pos < CAP) {
    token_list[te * CAP + pos] = idx / K_TOP;
    s = te * CAP + pos;
  }
  sid[idx] = s;
}

// ---------------- fused gate+up GEMM -> S = silu(g)*u (bf16) ----------------
// Pipelined: raw s_barrier + counted vmcnt BEFORE the consume-barrier, A
// double-buffered in LDS (global_load_lds, linear dest + source-side XOR
// swizzle), B regs prefetched 1 phase ahead, all LDS tiles XOR-swizzled on
// the 16B-chunk index -> 2-way (free) bank access.
__global__ __launch_bounds__(256) void gateup_kernel(
    const short* __restrict__ Xb, const float* __restrict__ Wg, const float* __restrict__ Wu,
    short* __restrict__ Sout, const int* __restrict__ tlist, const int* __restrict__ cnt_dev,
    int Nld, long long wstride, long long sstride) {
  int e = blockIdx.z;
  int cnt = cnt_dev ? cnt_dev[e] : T_TOK;
  int row0 = blockIdx.y * 128;
  if (row0 >= cnt) return;
  int col0 = blockIdx.x * 64;
  const float* wg = Wg + (long long)e * wstride;
  const float* wu = Wu + (long long)e * wstride;
  short* sbase = Sout + (long long)e * sstride;

  __shared__ __align__(16) short As[2][128 * 32];  // 16 KB (double-buffered)
  __shared__ __align__(16) short Bgs[64 * 32];     // 4 KB
  __shared__ __align__(16) short Bus[64 * 32];     // 4 KB

  int tid = threadIdx.x;
  int lane = tid & 63, wave = tid >> 6;

  // A staging (global_load_lds): row rr, 16B chunk ch; swizzle applied on SOURCE addr
  int rr = tid >> 2, ch = tid & 3;
  int che = ch ^ ((rr >> 1) & 3);
  int ra0 = row0 + rr, ra1 = ra0 + 64;
  if (tlist) {
    const int* tl = tlist + e * CAP;
    ra0 = tl[min(ra0, cnt - 1)];
    ra1 = tl[min(ra1, cnt - 1)];
  }
  const short* pa0 = Xb + (size_t)ra0 * H + che * 8;
  const short* pa1 = Xb + (size_t)ra1 * H + che * 8;
  short* ldsA00 = &As[0][(wave * 16) * 32];
  short* ldsA10 = &As[0][(64 + wave * 16) * 32];
  short* ldsA01 = &As[1][(wave * 16) * 32];
  short* ldsA11 = &As[1][(64 + wave * 16) * 32];

  // B staging: n = lane (coalesced), k-octet = wave; LDS chunk swizzled
  int bn = lane;
  const float* pg = wg + (size_t)(wave * 8) * Nld + col0 + bn;
  const float* pu = wu + (size_t)(wave * 8) * Nld + col0 + bn;
  int kswz = (wave ^ ((bn >> 1) & 3)) * 8;
  short* ldsBg = &Bgs[bn * 32 + kswz];
  short* ldsBu = &Bus[bn * 32 + kswz];

  int wm = wave & 1, wn = wave >> 1;
  int c = lane & 15, q = lane >> 4;
  int qa = q ^ ((c >> 1) & 3);  // swizzled chunk for fragment reads (per-thread const)
  const short* fA0 = &As[0][(wm * 64 + c) * 32 + qa * 8];
  const short* fA1 = &As[1][(wm * 64 + c) * 32 + qa * 8];
  const short* fBg = &Bgs[(wn * 32 + c) * 32 + qa * 8];
  const short* fBu = &Bus[(wn * 32 + c) * 32 + qa * 8];

  f32x4 accg[4][2], accu[4][2];
  #pragma unroll
  for (int i = 0; i < 4; ++i)
    #pragma unroll
    for (int j = 0; j < 2; ++j) {
      accg[i][j] = (f32x4){0.f, 0.f, 0.f, 0.f};
      accu[i][j] = (f32x4){0.f, 0.f, 0.f, 0.f};
    }

  // prologue: stage k=0 into buf0 (A gloads issued BEFORE B loads so in-order
  // vmcnt retirement of B implies A landed), load B(0) regs
  float gvA[8], uvA[8], gvB[8], uvB[8];
  gload_lds16(pa0, ldsA00);
  gload_lds16(pa1, ldsA10);
  #pragma unroll
  for (int j = 0; j < 8; ++j) {
    gvA[j] = pg[(size_t)j * Nld];
    uvA[j] = pu[(size_t)j * Nld];
  }

// One pipeline phase: compute K-slice KC from FAC/Bgs/Bus, prefetch KC+32.
// Per phase each wave issues 2 gload_lds + 16 global loads = 18 vmem ops;
// vmcnt(18) BEFORE the consume-barrier retires everything older (i.e. all of
// the previous phase, incl. the gload_lds into the buffer read after the
// barrier) while keeping this phase's 18 in flight across the barrier.
#define GU_PHASE(KC, FAC, LA0, LA1, GC, UC, GN, UN, PREF)                           \
  {                                                                                 \
    __builtin_amdgcn_s_barrier();                                                   \
    asm volatile("" ::: "memory");                                                  \
    if (PREF) {                                                                     \
      gload_lds16(pa0 + (KC) + 32, LA0);                                            \
      gload_lds16(pa1 + (KC) + 32, LA1);                                            \
      const float* pgk = pg + (size_t)((KC) + 32) * Nld;                            \
      const float* puk = pu + (size_t)((KC) + 32) * Nld;                            \
      _Pragma("unroll")                                                             \
      for (int j = 0; j < 8; ++j) {                                                 \
        GN[j] = pgk[(size_t)j * Nld];                                               \
        UN[j] = puk[(size_t)j * Nld];                                               \
      }                                                                             \
    }                                                                               \
    uint4 wvg, wvu;                                                                 \
    wvg.x = packbf2(GC[0], GC[1]); wvg.y = packbf2(GC[2], GC[3]);                   \
    wvg.z = packbf2(GC[4], GC[5]); wvg.w = packbf2(GC[6], GC[7]);                   \
    wvu.x = packbf2(UC[0], UC[1]); wvu.y = packbf2(UC[2], UC[3]);                   \
    wvu.z = packbf2(UC[4], UC[5]); wvu.w = packbf2(UC[6], UC[7]);                   \
    *(uint4*)ldsBg = wvg;                                                           \
    *(uint4*)ldsBu = wvu;                                                           \
    asm volatile("s_waitcnt lgkmcnt(0)" ::: "memory");                              \
    asm volatile("s_waitcnt vmcnt(18)" ::: "memory");                               \
    __builtin_amdgcn_s_barrier();                                                   \
    __builtin_amdgcn_sched_barrier(0);                                              \
    short8v a[4], bg[2], bu[2];                                                     \
    _Pragma("unroll")                                                               \
    for (int mi = 0; mi < 4; ++mi) a[mi] = *(const short8v*)((FAC) + mi * 16 * 32); \
    _Pragma("unroll")                                                               \
    for (int ni = 0; ni < 2; ++ni) {                                                \
      bg[ni] = *(const short8v*)(fBg + ni * 16 * 32);                               \
      bu[ni] = *(const short8v*)(fBu + ni * 16 * 32);                               \
    }                                                                               \
    _Pragma("unroll")                                                               \
    for (int mi = 0; mi < 4; ++mi)                                                  \
      _Pragma("unroll")                                                             \
      for (int ni = 0; ni < 2; ++ni) {                                              \
        accg[mi][ni] = __builtin_amdgcn_mfma_f32_16x16x32_bf16(a[mi], bg[ni], accg[mi][ni], 0, 0, 0); \
        accu[mi][ni] = __builtin_amdgcn_mfma_f32_16x16x32_bf16(a[mi], bu[ni], accu[mi][ni], 0, 0, 0); \
      }                                                                             \
  }

  for (int k0 = 0; k0 < H; k0 += 64) {
    GU_PHASE(k0,      fA0, ldsA01, ldsA11, gvA, uvA, gvB, uvB, true);
    GU_PHASE(k0 + 32, fA1, ldsA00, ldsA10, gvB, uvB, gvA, uvA, (k0 + 64 < H));
  }
#undef GU_PHASE

  #pragma unroll
  for (int mi = 0; mi < 4; ++mi) {
    int rbase = row0 + wm * 64 + mi * 16 + q * 4;
    #pragma unroll
    for (int ni = 0; ni < 2; ++ni) {
      int col = col0 + wn * 32 + ni * 16 + c;
      #pragma unroll
      for (int r = 0; r < 4; ++r) {
        float g = accg[mi][ni][r], u = accu[mi][ni][r];
        float s = (g / (1.f + __expf(-g))) * u;
        sbase[(size_t)(rbase + r) * Nld + col] = (short)f2bfbits(s);
      }
    }
  }
}

// ---------------- down GEMM: Y = S @ Wd (fp32 [K][H] native); pipelined like gateup ----
__global__ __launch_bounds__(256) void down_kernel(
    const short* __restrict__ Sin, const float* __restrict__ Wd,
    float* __restrict__ outF, short* __restrict__ outY,
    const int* __restrict__ cnt_dev, int Kdim, long long wstride, long long sstride) {
  int e = blockIdx.z;
  int cnt = cnt_dev ? cnt_dev[e] : T_TOK;
  int row0 = blockIdx.y * 128;
  if (row0 >= cnt) return;
  int col0 = blockIdx.x * 128;
  const short* sb = Sin + (long long)e * sstride;
  const float* wd = Wd + (long long)e * wstride;

  __shared__ __align__(16) short As[2][128 * 32];  // 16 KB
  __shared__ __align__(16) short Bs[128 * 32];     // 8 KB

  int tid = threadIdx.x;
  int lane = tid & 63, wave = tid >> 6;
  int rr = tid >> 2, ch = tid & 3;
  int che = ch ^ ((rr >> 1) & 3);

  const short* pa0 = sb + (size_t)(row0 + rr) * Kdim + che * 8;
  const short* pa1 = pa0 + (size_t)64 * Kdim;
  short* ldsA00 = &As[0][(wave * 16) * 32];
  short* ldsA10 = &As[0][(64 + wave * 16) * 32];
  short* ldsA01 = &As[1][(wave * 16) * 32];
  short* ldsA11 = &As[1][(64 + wave * 16) * 32];

  // B staging: n = tid&127 (coalesced per wave), two 16B chunks per thread (swizzled)
  int bn = tid & 127, w2 = tid >> 7;
  const float* pb = wd + (size_t)(w2 * 16) * H + col0 + bn;
  int bs = (bn >> 1) & 3;
  short* ldsB0 = &Bs[bn * 32 + ((w2 * 2) ^ bs) * 8];
  short* ldsB1 = &Bs[bn * 32 + ((w2 * 2 + 1) ^ bs) * 8];

  int wm = wave & 1, wn = wave >> 1;
  int c = lane & 15, q = lane >> 4;
  int qa = q ^ ((c >> 1) & 3);
  const short* fA0 = &As[0][(wm * 64 + c) * 32 + qa * 8];
  const short* fA1 = &As[1][(wm * 64 + c) * 32 + qa * 8];
  const short* fB  = &Bs[(wn * 64 + c) * 32 + qa * 8];

  f32x4 acc[4][4];
  #pragma unroll
  for (int i = 0; i < 4; ++i)
    #pragma unroll
    for (int j = 0; j < 4; ++j) acc[i][j] = (f32x4){0.f, 0.f, 0.f, 0.f};

  float bvA[16], bvB[16];
  gload_lds16(pa0, ldsA00);
  gload_lds16(pa1, ldsA10);
  #pragma unroll
  for (int j = 0; j < 16; ++j) bvA[j] = pb[(size_t)j * H];

#define DN_PHASE(KC, FAC, LA0, LA1, BC, BND, PREF)                                  \
  {                                                                                 \
    __builtin_amdgcn_s_barrier();                                                   \
    asm volatile("" ::: "memory");                                                  \
    if (PREF) {                                                                     \
      gload_lds16(pa0 + (KC) + 32, LA0);                                            \
      gload_lds16(pa1 + (KC) + 32, LA1);                                            \
      const float* pbk = pb + (size_t)((KC) + 32) * H;                              \
      _Pragma("unroll")                                                             \
      for (int j = 0; j < 16; ++j) BND[j] = pbk[(size_t)j * H];                     \
    }                                                                               \
    uint4 w0, w1;                                                                   \
    w0.x = packbf2(BC[0], BC[1]);   w0.y = packbf2(BC[2], BC[3]);                   \
    w0.z = packbf2(BC[4], BC[5]);   w0.w = packbf2(BC[6], BC[7]);                   \
    w1.x = packbf2(BC[8], BC[9]);   w1.y = packbf2(BC[10], BC[11]);                 \
    w1.z = packbf2(BC[12], BC[13]); w1.w = packbf2(BC[14], BC[15]);                 \
    *(uint4*)ldsB0 = w0;                                                            \
    *(uint4*)ldsB1 = w1;                                                            \
    asm volatile("s_waitcnt lgkmcnt(0)" ::: "memory");                              \
    asm volatile("s_waitcnt vmcnt(18)" ::: "memory");                               \
    __builtin_amdgcn_s_barrier();                                                   \
    __builtin_amdgcn_sched_barrier(0);                                              \
    short8v a[4], b[4];                                                             \
    _Pragma("unroll")                                                               \
    for (int mi = 0; mi < 4; ++mi) a[mi] = *(const short8v*)((FAC) + mi * 16 * 32); \
    _Pragma("unroll")                                                               \
    for (int ni = 0; ni < 4; ++ni) b[ni] = *(const short8v*)(fB + ni * 16 * 32);    \
    _Pragma("unroll")                                                               \
    for (int mi = 0; mi < 4; ++mi)                                                  \
      _Pragma("unroll")                                                             \
      for (int ni = 0; ni < 4; ++ni)                                                \
        acc[mi][ni] = __builtin_amdgcn_mfma_f32_16x16x32_bf16(a[mi], b[ni], acc[mi][ni], 0, 0, 0); \
  }

  for (int k0 = 0; k0 < Kdim; k0 += 64) {
    DN_PHASE(k0,      fA0, ldsA01, ldsA11, bvA, bvB, true);
    DN_PHASE(k0 + 32, fA1, ldsA00, ldsA10, bvB, bvA, (k0 + 64 < Kdim));
  }
#undef DN_PHASE

  if (outY) {
    // routed: plain bf16 stores into slot buffer rows e*CAP + row
    #pragma unroll
    for (int mi = 0; mi < 4; ++mi) {
      int rb = row0 + wm * 64 + mi * 16 + q * 4;
      #pragma unroll
      for (int r = 0; r < 4; ++r) {
        short* yrow = outY + (size_t)(e * CAP + rb + r) * H;
        #pragma unroll
        for (int ni = 0; ni < 4; ++ni) {
          int col = col0 + wn * 64 + ni * 16 + c;
          yrow[col] = (short)f2bfbits(acc[mi][ni][r]);
        }
      }
    }
  } else {
    #pragma unroll
    for (int mi = 0; mi < 4; ++mi) {
      int rb = row0 + wm * 64 + mi * 16 + q * 4;
      #pragma unroll
      for (int ni = 0; ni < 4; ++ni) {
        int col = col0 + wn * 64 + ni * 16 + c;
        #pragma unroll
        for (int r = 0; r < 4; ++r)
          outF[(size_t)(rb + r) * H + col] = acc[mi][ni][r];
      }
    }
  }
}

// ---------------- combine: out[t] += sum_k w_k * Yr[sid_k] ----------------
__global__ __launch_bounds__(256) void combine_kernel(
    const short* __restrict__ Yr, const int* __restrict__ sid,
    const float* __restrict__ twt, float* __restrict__ out) {
  int t = blockIdx.x;
  int col = threadIdx.x * 4;
  float* op = out + (size_t)t * H + col;
  float4 o = *(float4*)op;
  #pragma unroll
  for (int k = 0; k < K_TOP; ++k) {
    int s = sid[t * K_TOP + k];
    if (s >= 0) {
      float w = twt[t * K_TOP + k];
      ushort4 y = *(const ushort4*)(Yr + (size_t)s * H + col);
      o.x += w * bf2f(y.x);
      o.y += w * bf2f(y.y);
      o.z += w * bf2f(y.z);
      o.w += w * bf2f(y.w);
    }
  }
  *(float4*)op = o;
}

extern "C" void kernel_launch(void* const* d_in, const int* in_sizes, int n_in,
                              void* d_out, int out_size, void* d_ws, size_t ws_size,
                              hipStream_t stream) {
  const float* x       = (const float*)d_in[0];
  const float* gate_w  = (const float*)d_in[1];
  const float* w_gate  = (const float*)d_in[2];
  const float* w_up    = (const float*)d_in[3];
  const float* w_down  = (const float*)d_in[4];
  const float* sw_gate = (const float*)d_in[5];
  const float* sw_up   = (const float*)d_in[6];
  const float* sw_down = (const float*)d_in[7];
  float* out = (float*)d_out;
  char* ws = (char*)d_ws;

  size_t o = 0;
  short* xb   = (short*)(ws + o); o += (size_t)T_TOK * H * 2;          // 4 MB
  short* Sr   = (short*)(ws + o); o += (size_t)E * CAP * I_DIM * 2;    // 33 MB
  short* Ss   = (short*)(ws + o); o += (size_t)T_TOK * IS_DIM * 2;     // 5.5 MB
  short* Yr   = (short*)(ws + o); o += (size_t)E * CAP * H * 2;        // 48 MB
  int*   tidx = (int*)(ws + o);   o += (size_t)T_TOK * K_TOP * 4;
  float* twt  = (float*)(ws + o); o += (size_t)T_TOK * K_TOP * 4;
  int*   sid  = (int*)(ws + o);   o += (size_t)T_TOK * K_TOP * 4;
  int*   tl   = (int*)(ws + o);   o += (size_t)E * CAP * 4;
  int*   cnt  = (int*)(ws + o);   o += 256;
  int*   chist = (int*)(ws + o);  o += (size_t)NCHUNK * E * 4;
  int*   cbase = (int*)(ws + o);  o += (size_t)NCHUNK * E * 4;

  cast_x_kernel<<<(T_TOK * H) / 1024, 256, 0, stream>>>(x, xb);
  gating_kernel<<<T_TOK, 64, 0, stream>>>(x, gate_w, tidx, twt);
  hist_kernel<<<NCHUNK, 64, 0, stream>>>(tidx, chist);
  scan_kernel<<<1, 1024, 0, stream>>>(chist, cbase, cnt);
  place_kernel<<<NCHUNK, 64, 0, stream>>>(tidx, cbase, tl, sid);

  // routed gate+up -> Sr (B = w_gate/w_up fp32, native [H][I] layout)
  gateup_kernel<<<dim3(I_DIM / 64, CAP / 128, E), 256, 0, stream>>>(
      xb, w_gate, w_up, Sr, tl, cnt, I_DIM, (long long)H * I_DIM, (long long)CAP * I_DIM);
  // shared gate+up -> Ss
  gateup_kernel<<<dim3(IS_DIM / 64, T_TOK / 128, 1), 256, 0, stream>>>(
      xb, sw_gate, sw_up, Ss, nullptr, nullptr, IS_DIM, 0, 0);
  // shared down: fp32 store, fully initializes out
  down_kernel<<<dim3(H / 128, T_TOK / 128, 1), 256, 0, stream>>>(
      Ss, sw_down, out, nullptr, nullptr, IS_DIM, 0, 0);
  // routed down: bf16 stores into slot buffer
  down_kernel<<<dim3(H / 128, CAP / 128, E), 256, 0, stream>>>(
      Sr, w_down, nullptr, Yr, cnt, I_DIM, (long long)I_DIM * H, (long long)CAP * I_DIM);
  // final combine
  combine_kernel<<<T_TOK, 256, 0, stream>>>(Yr, sid, twt, out);
}